// Round 1
// baseline (1501.918 us; speedup 1.0000x reference)
//
#include <hip/hip_runtime.h>

// GIN fused: msg = node_feat[src] + edge_feat; agg = segment_sum(msg, dst);
// out = relu(agg@w1+b1)@w2+b2
// N=50000 nodes, E=800000 edges, H=128.

constexpr int NN = 50000;
constexpr long long NE = 800000;
constexpr int H  = 128;   // hidden
constexpr int H2 = 256;   // 2*hidden
constexpr int NPB = 16;   // nodes per block in MLP kernel

// ---------------------------------------------------------------------------
// Kernel 1: per-edge message + atomic scatter-add into agg[N][H].
// Thread layout: 32 float4-chunks per edge; lanes 0..31 of a wave cover one
// edge row (512 B contiguous), lanes 32..63 the next edge -> coalesced.
// ---------------------------------------------------------------------------
__global__ __launch_bounds__(256) void scatter_kernel(
    const float* __restrict__ node_feat,
    const float* __restrict__ edge_feat,
    const int*   __restrict__ edge_src,
    const int*   __restrict__ edge_dst,
    float*       __restrict__ agg)
{
    long long tid = (long long)blockIdx.x * blockDim.x + threadIdx.x;
    const long long total = NE * 32;   // 32 float4 per edge
    if (tid >= total) return;
    int e = (int)(tid >> 5);
    int q = (int)((tid & 31) << 2);    // float offset within the 128-wide row
    int s = edge_src[e];
    int d = edge_dst[e];
    const float4 nf = *(const float4*)(node_feat + (long long)s * H + q);
    const float4 ef = *(const float4*)(edge_feat + (long long)e * H + q);
    float* dst = agg + (long long)d * H + q;
    atomicAdd(dst + 0, nf.x + ef.x);
    atomicAdd(dst + 1, nf.y + ef.y);
    atomicAdd(dst + 2, nf.z + ef.z);
    atomicAdd(dst + 3, nf.w + ef.w);
}

// ---------------------------------------------------------------------------
// Kernel 2: 2-layer MLP, 16 nodes per 256-thread block.
// Layer1: thread t owns h-column t (0..255), 16 accumulators (one per node),
// each w1 element loaded once and reused 16x. Layer2: thread t owns out
// column (t&127) for 8 of the 16 nodes (t>>7 selects the half).
// ---------------------------------------------------------------------------
__global__ __launch_bounds__(256) void mlp_kernel(
    const float* __restrict__ agg,
    const float* __restrict__ w1, const float* __restrict__ b1,
    const float* __restrict__ w2, const float* __restrict__ b2,
    float*       __restrict__ out)
{
    __shared__ float s_in[NPB][H];    // 16*128*4 = 8 KB
    __shared__ float s_h [NPB][H2];   // 16*256*4 = 16 KB
    const int t = threadIdx.x;
    const long long base = (long long)blockIdx.x * NPB;

    // stage 16 agg rows: 2048 floats = 512 float4; 2 per thread, coalesced
    {
        const float4* src = (const float4*)(agg + base * H);
        float4* dst = (float4*)(&s_in[0][0]);
        dst[t]       = src[t];
        dst[t + 256] = src[t + 256];
    }
    __syncthreads();

    // ---- layer 1: h = relu(agg @ w1 + b1), thread t -> column t of h ----
    float acc[NPB];
    {
        const float b = b1[t];
        #pragma unroll
        for (int n = 0; n < NPB; ++n) acc[n] = b;
    }
    #pragma unroll 4
    for (int k = 0; k < H; ++k) {
        const float w = w1[k * H2 + t];          // coalesced across threads
        #pragma unroll
        for (int n = 0; n < NPB; ++n)
            acc[n] = fmaf(s_in[n][k], w, acc[n]); // LDS broadcast
    }
    #pragma unroll
    for (int n = 0; n < NPB; ++n) s_h[n][t] = fmaxf(acc[n], 0.0f);
    __syncthreads();

    // ---- layer 2: out = h @ w2 + b2 ----
    const int j = t & (H - 1);
    const int g = t >> 7;                 // 0 or 1 -> node half
    float acc2[NPB / 2];
    {
        const float b = b2[j];
        #pragma unroll
        for (int n = 0; n < NPB / 2; ++n) acc2[n] = b;
    }
    #pragma unroll 4
    for (int k = 0; k < H2; ++k) {
        const float w = w2[k * H + j];
        #pragma unroll
        for (int n = 0; n < NPB / 2; ++n)
            acc2[n] = fmaf(s_h[g * (NPB / 2) + n][k], w, acc2[n]);
    }
    #pragma unroll
    for (int n = 0; n < NPB / 2; ++n)
        out[(base + g * (NPB / 2) + n) * H + j] = acc2[n];
}

// ---------------------------------------------------------------------------
extern "C" void kernel_launch(void* const* d_in, const int* in_sizes, int n_in,
                              void* d_out, int out_size, void* d_ws, size_t ws_size,
                              hipStream_t stream)
{
    const float* node_feat = (const float*)d_in[0];
    const float* edge_feat = (const float*)d_in[1];
    const int*   edge_src  = (const int*)  d_in[2];
    const int*   edge_dst  = (const int*)  d_in[3];
    const float* w1 = (const float*)d_in[4];
    const float* b1 = (const float*)d_in[5];
    const float* w2 = (const float*)d_in[6];
    const float* b2 = (const float*)d_in[7];
    float* out = (float*)d_out;

    const size_t agg_bytes = (size_t)NN * H * sizeof(float);  // 25.6 MB
    // agg lives in workspace if it fits; otherwise compute it in-place in
    // d_out (same shape/size as out; MLP stages rows to LDS before writing).
    float* agg = (ws_size >= agg_bytes) ? (float*)d_ws : out;

    hipMemsetAsync(agg, 0, agg_bytes, stream);

    {   // scatter: NE*32 work items
        const long long total = NE * 32;
        const int block = 256;
        const int grid  = (int)((total + block - 1) / block);   // 100000
        scatter_kernel<<<grid, block, 0, stream>>>(
            node_feat, edge_feat, edge_src, edge_dst, agg);
    }
    {   // MLP: 16 nodes per block
        const int grid = NN / NPB;   // 3125 (50000 divisible by 16)
        mlp_kernel<<<grid, 256, 0, stream>>>(agg, w1, b1, w2, b2, out);
    }
}

// Round 2
// 483.084 us; speedup vs baseline: 3.1090x; 3.1090x over previous
//
#include <hip/hip_runtime.h>

// GIN fused: msg = node_feat[src] + edge_feat; agg = segment_sum(msg, dst);
// out = relu(agg@w1+b1)@w2+b2
// N=50000 nodes, E=800000 edges, H=128.
//
// Round 2: replace 102.4M fp32 atomicAdds (WRITE_SIZE was 1.6 GB, atomic-bound
// at 1350us) with on-device CSR build (int atomics only) + atomic-free gather.

constexpr int NN = 50000;
constexpr int NE = 800000;
constexpr int H  = 128;   // hidden
constexpr int H2 = 256;   // 2*hidden
constexpr int NPB = 16;   // nodes per block in MLP kernel

// ---------------------------------------------------------------------------
// CSR build step 1: histogram of edge_dst
// ---------------------------------------------------------------------------
__global__ __launch_bounds__(256) void count_kernel(
    const int* __restrict__ edge_dst, int* __restrict__ count)
{
    int e = blockIdx.x * blockDim.x + threadIdx.x;
    if (e < NE) atomicAdd(&count[edge_dst[e]], 1);
}

// ---------------------------------------------------------------------------
// CSR build step 2: exclusive prefix sum over count[NN] -> offsets[NN+1].
// Single block, 1024 threads, ~49 elements per thread.
// ---------------------------------------------------------------------------
__global__ __launch_bounds__(1024) void scan_kernel(
    const int* __restrict__ count, int* __restrict__ offsets)
{
    __shared__ int sums[1024];
    const int t  = threadIdx.x;
    const int CH = (NN + 1023) / 1024;          // 49
    const int beg = t * CH;
    const int end = (beg + CH < NN) ? beg + CH : NN;
    int s = 0;
    for (int i = beg; i < end; ++i) s += count[i];
    sums[t] = s;
    __syncthreads();
    // Hillis-Steele inclusive scan over 1024 partials
    for (int off = 1; off < 1024; off <<= 1) {
        int v = (t >= off) ? sums[t - off] : 0;
        __syncthreads();
        if (t >= off) sums[t] += v;
        __syncthreads();
    }
    int run = (t == 0) ? 0 : sums[t - 1];       // exclusive prefix
    for (int i = beg; i < end; ++i) { offsets[i] = run; run += count[i]; }
    if (t == 1023) offsets[NN] = run;           // == NE
}

// ---------------------------------------------------------------------------
// CSR build step 3: place edge ids grouped by destination
// ---------------------------------------------------------------------------
__global__ __launch_bounds__(256) void place_kernel(
    const int* __restrict__ edge_dst, const int* __restrict__ offsets,
    int* __restrict__ cursor, int* __restrict__ sorted_eid)
{
    int e = blockIdx.x * blockDim.x + threadIdx.x;
    if (e < NE) {
        int d = edge_dst[e];
        int pos = offsets[d] + atomicAdd(&cursor[d], 1);
        sorted_eid[pos] = e;
    }
}

// ---------------------------------------------------------------------------
// Gather: one 64-lane wave per node, float2 per lane covers the 128-wide row.
// No atomics; each edge row read exactly once (512 B coalesced per wave).
// ---------------------------------------------------------------------------
__global__ __launch_bounds__(256) void gather_kernel(
    const float* __restrict__ node_feat,
    const float* __restrict__ edge_feat,
    const int*   __restrict__ edge_src,
    const int*   __restrict__ sorted_eid,
    const int*   __restrict__ offsets,
    float*       __restrict__ agg)
{
    const int node = blockIdx.x * 4 + (threadIdx.x >> 6);
    const int co   = (threadIdx.x & 63) * 2;
    const int start = offsets[node];
    const int end   = offsets[node + 1];
    float accx = 0.f, accy = 0.f;
    for (int i = start; i < end; ++i) {
        const int e = sorted_eid[i];          // wave-uniform -> scalar load
        const int s = edge_src[e];            // wave-uniform -> scalar load
        const float2 ef = *(const float2*)(edge_feat + (long long)e * H + co);
        const float2 nf = *(const float2*)(node_feat + (long long)s * H + co);
        accx += ef.x + nf.x;
        accy += ef.y + nf.y;
    }
    float2* dst = (float2*)(agg + (long long)node * H + co);
    dst->x = accx;
    dst->y = accy;
}

// ---------------------------------------------------------------------------
// Fallback scatter (round-1 path) if workspace is too small for CSR.
// ---------------------------------------------------------------------------
__global__ __launch_bounds__(256) void scatter_kernel(
    const float* __restrict__ node_feat,
    const float* __restrict__ edge_feat,
    const int*   __restrict__ edge_src,
    const int*   __restrict__ edge_dst,
    float*       __restrict__ agg)
{
    long long tid = (long long)blockIdx.x * blockDim.x + threadIdx.x;
    const long long total = (long long)NE * 32;
    if (tid >= total) return;
    int e = (int)(tid >> 5);
    int q = (int)((tid & 31) << 2);
    int s = edge_src[e];
    int d = edge_dst[e];
    const float4 nf = *(const float4*)(node_feat + (long long)s * H + q);
    const float4 ef = *(const float4*)(edge_feat + (long long)e * H + q);
    float* dst = agg + (long long)d * H + q;
    atomicAdd(dst + 0, nf.x + ef.x);
    atomicAdd(dst + 1, nf.y + ef.y);
    atomicAdd(dst + 2, nf.z + ef.z);
    atomicAdd(dst + 3, nf.w + ef.w);
}

// ---------------------------------------------------------------------------
// MLP: 16 nodes per 256-thread block (unchanged from round 1).
// ---------------------------------------------------------------------------
__global__ __launch_bounds__(256) void mlp_kernel(
    const float* __restrict__ agg,
    const float* __restrict__ w1, const float* __restrict__ b1,
    const float* __restrict__ w2, const float* __restrict__ b2,
    float*       __restrict__ out)
{
    __shared__ float s_in[NPB][H];    // 8 KB
    __shared__ float s_h [NPB][H2];   // 16 KB
    const int t = threadIdx.x;
    const long long base = (long long)blockIdx.x * NPB;

    {
        const float4* src = (const float4*)(agg + base * H);
        float4* dst = (float4*)(&s_in[0][0]);
        dst[t]       = src[t];
        dst[t + 256] = src[t + 256];
    }
    __syncthreads();

    float acc[NPB];
    {
        const float b = b1[t];
        #pragma unroll
        for (int n = 0; n < NPB; ++n) acc[n] = b;
    }
    #pragma unroll 4
    for (int k = 0; k < H; ++k) {
        const float w = w1[k * H2 + t];
        #pragma unroll
        for (int n = 0; n < NPB; ++n)
            acc[n] = fmaf(s_in[n][k], w, acc[n]);
    }
    #pragma unroll
    for (int n = 0; n < NPB; ++n) s_h[n][t] = fmaxf(acc[n], 0.0f);
    __syncthreads();

    const int j = t & (H - 1);
    const int g = t >> 7;
    float acc2[NPB / 2];
    {
        const float b = b2[j];
        #pragma unroll
        for (int n = 0; n < NPB / 2; ++n) acc2[n] = b;
    }
    #pragma unroll 4
    for (int k = 0; k < H2; ++k) {
        const float w = w2[k * H + j];
        #pragma unroll
        for (int n = 0; n < NPB / 2; ++n)
            acc2[n] = fmaf(s_h[g * (NPB / 2) + n][k], w, acc2[n]);
    }
    #pragma unroll
    for (int n = 0; n < NPB / 2; ++n)
        out[(base + g * (NPB / 2) + n) * H + j] = acc2[n];
}

// ---------------------------------------------------------------------------
extern "C" void kernel_launch(void* const* d_in, const int* in_sizes, int n_in,
                              void* d_out, int out_size, void* d_ws, size_t ws_size,
                              hipStream_t stream)
{
    const float* node_feat = (const float*)d_in[0];
    const float* edge_feat = (const float*)d_in[1];
    const int*   edge_src  = (const int*)  d_in[2];
    const int*   edge_dst  = (const int*)  d_in[3];
    const float* w1 = (const float*)d_in[4];
    const float* b1 = (const float*)d_in[5];
    const float* w2 = (const float*)d_in[6];
    const float* b2 = (const float*)d_in[7];
    float* out = (float*)d_out;

    // Workspace layout (256-B aligned regions)
    const size_t count_b   = ((size_t)NN * 4 + 255) & ~(size_t)255;       // 200 KB
    const size_t cursor_b  = count_b;                                      // 200 KB
    const size_t offs_b    = (((size_t)NN + 1) * 4 + 255) & ~(size_t)255;  // 200 KB
    const size_t eid_b     = ((size_t)NE * 4 + 255) & ~(size_t)255;        // 3.2 MB
    const size_t agg_b     = (size_t)NN * H * sizeof(float);               // 25.6 MB
    const size_t need      = count_b + cursor_b + offs_b + eid_b + agg_b;  // ~29.4 MB

    if (ws_size >= need) {
        char* p = (char*)d_ws;
        int*   count      = (int*)p;              p += count_b;
        int*   cursor     = (int*)p;              p += cursor_b;
        int*   offsets    = (int*)p;              p += offs_b;
        int*   sorted_eid = (int*)p;              p += eid_b;
        float* agg        = (float*)p;

        // zero the histogram + cursors (contiguous at start of ws)
        hipMemsetAsync(d_ws, 0, count_b + cursor_b, stream);

        const int eb = 256, eg = (NE + eb - 1) / eb;   // 3125
        count_kernel<<<eg, eb, 0, stream>>>(edge_dst, count);
        scan_kernel<<<1, 1024, 0, stream>>>(count, offsets);
        place_kernel<<<eg, eb, 0, stream>>>(edge_dst, offsets, cursor, sorted_eid);
        gather_kernel<<<NN / 4, 256, 0, stream>>>(
            node_feat, edge_feat, edge_src, sorted_eid, offsets, agg);
        mlp_kernel<<<NN / NPB, 256, 0, stream>>>(agg, w1, b1, w2, b2, out);
    } else {
        // Fallback: round-1 atomic path
        const size_t agg_bytes = (size_t)NN * H * sizeof(float);
        float* agg = (ws_size >= agg_bytes) ? (float*)d_ws : out;
        hipMemsetAsync(agg, 0, agg_bytes, stream);
        const long long total = (long long)NE * 32;
        const int block = 256;
        const int grid  = (int)((total + block - 1) / block);
        scatter_kernel<<<grid, block, 0, stream>>>(
            node_feat, edge_feat, edge_src, edge_dst, agg);
        mlp_kernel<<<NN / NPB, 256, 0, stream>>>(agg, w1, b1, w2, b2, out);
    }
}

// Round 3
// 449.323 us; speedup vs baseline: 3.3426x; 1.0751x over previous
//
#include <hip/hip_runtime.h>

// GIN fused: msg = node_feat[src] + edge_feat; agg = segment_sum(msg, dst);
// out = relu(agg@w1+b1)@w2+b2
// N=50000 nodes, E=800000 edges, H=128.
//
// Round 3: replace 400KB hipMemsetAsync (pathological 240us fillBuffer in the
// captured graph) with a custom zero kernel; store (eid,src) int2 in CSR to
// shorten the gather dependent-load chain.

constexpr int NN = 50000;
constexpr int NE = 800000;
constexpr int H  = 128;   // hidden
constexpr int H2 = 256;   // 2*hidden
constexpr int NPB = 16;   // nodes per block in MLP kernel

// ---------------------------------------------------------------------------
// Zero the count+cursor arrays (2*50000 ints, padded region) -- replaces the
// 240us fillBufferAligned.
// ---------------------------------------------------------------------------
__global__ __launch_bounds__(256) void zero_kernel(int4* __restrict__ p, int n4)
{
    int i = blockIdx.x * blockDim.x + threadIdx.x;
    if (i < n4) p[i] = make_int4(0, 0, 0, 0);
}

// ---------------------------------------------------------------------------
// CSR build step 1: histogram of edge_dst
// ---------------------------------------------------------------------------
__global__ __launch_bounds__(256) void count_kernel(
    const int* __restrict__ edge_dst, int* __restrict__ count)
{
    int e = blockIdx.x * blockDim.x + threadIdx.x;
    if (e < NE) atomicAdd(&count[edge_dst[e]], 1);
}

// ---------------------------------------------------------------------------
// CSR build step 2: exclusive prefix sum over count[NN] -> offsets[NN+1].
// ---------------------------------------------------------------------------
__global__ __launch_bounds__(1024) void scan_kernel(
    const int* __restrict__ count, int* __restrict__ offsets)
{
    __shared__ int sums[1024];
    const int t  = threadIdx.x;
    const int CH = (NN + 1023) / 1024;          // 49
    const int beg = t * CH;
    const int end = (beg + CH < NN) ? beg + CH : NN;
    int s = 0;
    for (int i = beg; i < end; ++i) s += count[i];
    sums[t] = s;
    __syncthreads();
    for (int off = 1; off < 1024; off <<= 1) {
        int v = (t >= off) ? sums[t - off] : 0;
        __syncthreads();
        if (t >= off) sums[t] += v;
        __syncthreads();
    }
    int run = (t == 0) ? 0 : sums[t - 1];       // exclusive prefix
    for (int i = beg; i < end; ++i) { offsets[i] = run; run += count[i]; }
    if (t == 1023) offsets[NN] = run;           // == NE
}

// ---------------------------------------------------------------------------
// CSR build step 3: place (eid, src) pairs grouped by destination
// ---------------------------------------------------------------------------
__global__ __launch_bounds__(256) void place_kernel(
    const int* __restrict__ edge_dst, const int* __restrict__ edge_src,
    const int* __restrict__ offsets,
    int* __restrict__ cursor, int2* __restrict__ sorted_es)
{
    int e = blockIdx.x * blockDim.x + threadIdx.x;
    if (e < NE) {
        int d = edge_dst[e];
        int pos = offsets[d] + atomicAdd(&cursor[d], 1);
        sorted_es[pos] = make_int2(e, edge_src[e]);
    }
}

// ---------------------------------------------------------------------------
// Gather: one 64-lane wave per node, float2 per lane covers the 128-wide row.
// No atomics; each edge row read exactly once (512 B coalesced per wave).
// ---------------------------------------------------------------------------
__global__ __launch_bounds__(256) void gather_kernel(
    const float* __restrict__ node_feat,
    const float* __restrict__ edge_feat,
    const int2*  __restrict__ sorted_es,
    const int*   __restrict__ offsets,
    float*       __restrict__ agg)
{
    const int node = blockIdx.x * 4 + (threadIdx.x >> 6);
    const int co   = (threadIdx.x & 63) * 2;
    const int start = offsets[node];
    const int end   = offsets[node + 1];
    float accx = 0.f, accy = 0.f;
    for (int i = start; i < end; ++i) {
        const int2 es = sorted_es[i];         // wave-uniform
        const float2 ef = *(const float2*)(edge_feat + (long long)es.x * H + co);
        const float2 nf = *(const float2*)(node_feat + (long long)es.y * H + co);
        accx += ef.x + nf.x;
        accy += ef.y + nf.y;
    }
    float2* dst = (float2*)(agg + (long long)node * H + co);
    dst->x = accx;
    dst->y = accy;
}

// ---------------------------------------------------------------------------
// MLP: 16 nodes per 256-thread block.
// ---------------------------------------------------------------------------
__global__ __launch_bounds__(256) void mlp_kernel(
    const float* __restrict__ agg,
    const float* __restrict__ w1, const float* __restrict__ b1,
    const float* __restrict__ w2, const float* __restrict__ b2,
    float*       __restrict__ out)
{
    __shared__ float s_in[NPB][H];    // 8 KB
    __shared__ float s_h [NPB][H2];   // 16 KB
    const int t = threadIdx.x;
    const long long base = (long long)blockIdx.x * NPB;

    {
        const float4* src = (const float4*)(agg + base * H);
        float4* dst = (float4*)(&s_in[0][0]);
        dst[t]       = src[t];
        dst[t + 256] = src[t + 256];
    }
    __syncthreads();

    float acc[NPB];
    {
        const float b = b1[t];
        #pragma unroll
        for (int n = 0; n < NPB; ++n) acc[n] = b;
    }
    #pragma unroll 4
    for (int k = 0; k < H; ++k) {
        const float w = w1[k * H2 + t];
        #pragma unroll
        for (int n = 0; n < NPB; ++n)
            acc[n] = fmaf(s_in[n][k], w, acc[n]);
    }
    #pragma unroll
    for (int n = 0; n < NPB; ++n) s_h[n][t] = fmaxf(acc[n], 0.0f);
    __syncthreads();

    const int j = t & (H - 1);
    const int g = t >> 7;
    float acc2[NPB / 2];
    {
        const float b = b2[j];
        #pragma unroll
        for (int n = 0; n < NPB / 2; ++n) acc2[n] = b;
    }
    #pragma unroll 4
    for (int k = 0; k < H2; ++k) {
        const float w = w2[k * H + j];
        #pragma unroll
        for (int n = 0; n < NPB / 2; ++n)
            acc2[n] = fmaf(s_h[g * (NPB / 2) + n][k], w, acc2[n]);
    }
    #pragma unroll
    for (int n = 0; n < NPB / 2; ++n)
        out[(base + g * (NPB / 2) + n) * H + j] = acc2[n];
}

// ---------------------------------------------------------------------------
// Fallback scatter (atomic path) if workspace is too small for CSR.
// ---------------------------------------------------------------------------
__global__ __launch_bounds__(256) void scatter_kernel(
    const float* __restrict__ node_feat,
    const float* __restrict__ edge_feat,
    const int*   __restrict__ edge_src,
    const int*   __restrict__ edge_dst,
    float*       __restrict__ agg)
{
    long long tid = (long long)blockIdx.x * blockDim.x + threadIdx.x;
    const long long total = (long long)NE * 32;
    if (tid >= total) return;
    int e = (int)(tid >> 5);
    int q = (int)((tid & 31) << 2);
    int s = edge_src[e];
    int d = edge_dst[e];
    const float4 nf = *(const float4*)(node_feat + (long long)s * H + q);
    const float4 ef = *(const float4*)(edge_feat + (long long)e * H + q);
    float* dst = agg + (long long)d * H + q;
    atomicAdd(dst + 0, nf.x + ef.x);
    atomicAdd(dst + 1, nf.y + ef.y);
    atomicAdd(dst + 2, nf.z + ef.z);
    atomicAdd(dst + 3, nf.w + ef.w);
}

__global__ __launch_bounds__(256) void zero_agg_kernel(float4* __restrict__ p, int n4)
{
    int i = blockIdx.x * blockDim.x + threadIdx.x;
    if (i < n4) p[i] = make_float4(0.f, 0.f, 0.f, 0.f);
}

// ---------------------------------------------------------------------------
extern "C" void kernel_launch(void* const* d_in, const int* in_sizes, int n_in,
                              void* d_out, int out_size, void* d_ws, size_t ws_size,
                              hipStream_t stream)
{
    const float* node_feat = (const float*)d_in[0];
    const float* edge_feat = (const float*)d_in[1];
    const int*   edge_src  = (const int*)  d_in[2];
    const int*   edge_dst  = (const int*)  d_in[3];
    const float* w1 = (const float*)d_in[4];
    const float* b1 = (const float*)d_in[5];
    const float* w2 = (const float*)d_in[6];
    const float* b2 = (const float*)d_in[7];
    float* out = (float*)d_out;

    // Workspace layout (256-B aligned regions)
    const size_t count_b   = ((size_t)NN * 4 + 255) & ~(size_t)255;       // 200 KB
    const size_t cursor_b  = count_b;                                      // 200 KB
    const size_t offs_b    = (((size_t)NN + 1) * 4 + 255) & ~(size_t)255;  // 200 KB
    const size_t es_b      = ((size_t)NE * 8 + 255) & ~(size_t)255;        // 6.4 MB
    const size_t agg_b     = (size_t)NN * H * sizeof(float);               // 25.6 MB
    const size_t need      = count_b + cursor_b + offs_b + es_b + agg_b;   // ~32.6 MB

    if (ws_size >= need) {
        char* p = (char*)d_ws;
        int*   count     = (int*)p;              p += count_b;
        int*   cursor    = (int*)p;              p += cursor_b;
        int*   offsets   = (int*)p;              p += offs_b;
        int2*  sorted_es = (int2*)p;             p += es_b;
        float* agg       = (float*)p;

        // zero histogram + cursors with our own kernel (NOT hipMemsetAsync --
        // the rocclr fillBuffer took 240us in the captured graph)
        {
            const int n4 = (int)((count_b + cursor_b) / 16);   // int4 count
            zero_kernel<<<(n4 + 255) / 256, 256, 0, stream>>>((int4*)d_ws, n4);
        }

        const int eb = 256, eg = (NE + eb - 1) / eb;   // 3125
        count_kernel<<<eg, eb, 0, stream>>>(edge_dst, count);
        scan_kernel<<<1, 1024, 0, stream>>>(count, offsets);
        place_kernel<<<eg, eb, 0, stream>>>(edge_dst, edge_src, offsets, cursor, sorted_es);
        gather_kernel<<<NN / 4, 256, 0, stream>>>(
            node_feat, edge_feat, sorted_es, offsets, agg);
        mlp_kernel<<<NN / NPB, 256, 0, stream>>>(agg, w1, b1, w2, b2, out);
    } else {
        // Fallback: atomic path
        const size_t agg_bytes = (size_t)NN * H * sizeof(float);
        float* agg = (ws_size >= agg_bytes) ? (float*)d_ws : out;
        {
            const int n4 = (int)(agg_bytes / 16);
            zero_agg_kernel<<<(n4 + 255) / 256, 256, 0, stream>>>((float4*)agg, n4);
        }
        const long long total = (long long)NE * 32;
        const int block = 256;
        const int grid  = (int)((total + block - 1) / block);
        scatter_kernel<<<grid, block, 0, stream>>>(
            node_feat, edge_feat, edge_src, edge_dst, agg);
        mlp_kernel<<<NN / NPB, 256, 0, stream>>>(agg, w1, b1, w2, b2, out);
    }
}